// Round 8
// baseline (269.955 us; speedup 1.0000x reference)
//
#include <hip/hip_runtime.h>
#include <stdint.h>

#define IN_C  256
#define HID   256
#define OUT_C 128
#define SCAN_BS 1024

typedef __bf16 bf16x8 __attribute__((ext_vector_type(8)));
typedef float  f32x4  __attribute__((ext_vector_type(4)));
typedef unsigned short u16x8 __attribute__((ext_vector_type(8)));
typedef unsigned short u16x4 __attribute__((ext_vector_type(4)));
typedef unsigned short u16x2 __attribute__((ext_vector_type(2)));
typedef unsigned int u32;

static __device__ __forceinline__ unsigned short f2b(float f) {
    union { float f; uint32_t u; } v; v.f = f;
    uint32_t r = v.u + 0x7fffu + ((v.u >> 16) & 1u);
    return (unsigned short)(r >> 16);
}
static __device__ __forceinline__ float b2f(unsigned short b) {
    union { uint32_t u; float f; } v; v.u = ((uint32_t)b) << 16;
    return v.f;
}
// pack 2 f32 -> u32 of 2 bf16 (RNE), 1 VALU op (proven correct R6/R7)
static __device__ __forceinline__ u32 cvtpk(float lo, float hi) {
    u32 r;
    asm("v_cvt_pk_bf16_f32 %0, %1, %2" : "=v"(r) : "v"(lo), "v"(hi));
    return r;
}

// ---------------- CSR build (self-loop folded in; per-edge weight precomputed) ----
__global__ void k_zero_i(int* __restrict__ p, int n) {
    int i = blockIdx.x * blockDim.x + threadIdx.x;
    if (i < n) p[i] = 0;
}

__global__ void k_count(const int* __restrict__ dst, int* __restrict__ cnt, int e) {
    int i = blockIdx.x * blockDim.x + threadIdx.x;
    if (i < e) atomicAdd(&cnt[dst[i]], 1);
}

__global__ __launch_bounds__(SCAN_BS) void k_scan_block(
    const int* __restrict__ cnt, int* __restrict__ rs, int* __restrict__ bsum, int n) {
    __shared__ int s[SCAN_BS];
    const int tid = threadIdx.x;
    const int i = blockIdx.x * SCAN_BS + tid;
    int v = (i < n) ? cnt[i] + 1 : 0;
    s[tid] = v;
    __syncthreads();
    for (int off = 1; off < SCAN_BS; off <<= 1) {
        int t = (tid >= off) ? s[tid - off] : 0;
        __syncthreads();
        s[tid] += t;
        __syncthreads();
    }
    if (i < n) rs[i] = s[tid] - v;
    if (tid == SCAN_BS - 1) bsum[blockIdx.x] = s[tid];
}

__global__ void k_scan_sums(int* __restrict__ bsum, int nb) {
    __shared__ int s[128];
    const int tid = threadIdx.x;
    int v = (tid < nb) ? bsum[tid] : 0;
    s[tid] = v;
    __syncthreads();
    for (int off = 1; off < 128; off <<= 1) {
        int t = (tid >= off) ? s[tid - off] : 0;
        __syncthreads();
        s[tid] += t;
        __syncthreads();
    }
    if (tid < nb) bsum[tid] = s[tid] - v;
}

__global__ void k_scan_add(int* __restrict__ rs, int* __restrict__ cur,
                           const int* __restrict__ bsum, const int* __restrict__ cnt,
                           float* __restrict__ dinv, int2* __restrict__ csrw, int n) {
    int i = blockIdx.x * blockDim.x + threadIdx.x;
    if (i < n) {
        int v = rs[i] + bsum[i >> 10];
        rs[i] = v;
        cur[i] = v + 1;
        float dp1 = (float)(cnt[i] + 1);
        dinv[i] = rsqrtf(dp1);
        csrw[v] = make_int2(i, __float_as_int(1.0f / dp1));   // self: weight = dinv^2
    }
}

__global__ void k_fill(const int* __restrict__ src, const int* __restrict__ dst,
                       const float* __restrict__ dinv,
                       int* __restrict__ cur, int2* __restrict__ csrw, int e) {
    int i = blockIdx.x * blockDim.x + threadIdx.x;
    if (i < e) {
        int s = src[i], d = dst[i];
        int p = atomicAdd(&cur[d], 1);
        csrw[p] = make_int2(s, __float_as_int(dinv[s] * dinv[d]));
    }
}

__global__ void k_prep(const float* __restrict__ W1, const float* __restrict__ W2,
                       unsigned short* __restrict__ W1T, unsigned short* __restrict__ W2T) {
    int i = blockIdx.x * blockDim.x + threadIdx.x;
    if (i < 65536) W1T[i] = f2b(W1[(i & 255) * HID + (i >> 8)]);
    if (i < 32768) W2T[i] = f2b(W2[(i & 255) * OUT_C + (i >> 8)]);
}

// ---------------- GEMM1: t1[n][256] bf16 = x(f32) @ W1 ----------------------
// Flat streaming GEMM. 1024 thr = 16 waves (4 row-streams x 4 col-waves).
// Full W1T panel (256x256 bf16 = 128 KiB) staged ONCE into LDS with XOR
// granule swizzle (g ^= col&7 on 16B granules; reg-staged write so write and
// read sides agree). ONE barrier total; then each wave streams A row-tiles
// from global (coalesced), converts f32->bf16 via v_cvt_pk_bf16_f32, and
// runs 32 register+LDS MFMAs per tile. No per-tile barriers.
__global__ __launch_bounds__(1024) void k_gemm1(
    const float* __restrict__ x, const unsigned short* __restrict__ W1T,
    unsigned short* __restrict__ t1, int n, int ntiles) {
    __shared__ __align__(16) unsigned short Bp[256 * 256];   // 128 KiB
    const int tid = threadIdx.x;
    #pragma unroll
    for (int it = 0; it < 8; ++it) {
        int gi = it * 1024 + tid;
        int col = gi >> 5, g = gi & 31;
        u16x8 v = *(const u16x8*)&W1T[col * 256 + g * 8];
        *(u16x8*)&Bp[col * 256 + ((g ^ (col & 7)) << 3)] = v;
    }
    __syncthreads();
    const int wid = tid >> 6, lane = tid & 63;
    const int rg = wid >> 2;
    const int wc0 = (wid & 3) << 6;
    const int lrow = lane & 15, lgrp = lane >> 4;

    for (int t = blockIdx.x * 4 + rg; t < ntiles; t += 1024) {
        int ar = t * 16 + lrow; if (ar >= n) ar = n - 1;
        const float* ap = x + (size_t)ar * 256 + lgrp * 8;
        f32x4 lo[8], hi[8];
        #pragma unroll
        for (int kk = 0; kk < 8; ++kk) {
            lo[kk] = *(const f32x4*)(ap + kk * 32);
            hi[kk] = *(const f32x4*)(ap + kk * 32 + 4);
        }
        f32x4 acc[4];
        #pragma unroll
        for (int nf = 0; nf < 4; ++nf) acc[nf] = (f32x4){0.f, 0.f, 0.f, 0.f};
        #pragma unroll
        for (int kk = 0; kk < 8; ++kk) {
            union { u32 w[4]; bf16x8 v; } a;
            a.w[0] = cvtpk(lo[kk][0], lo[kk][1]);
            a.w[1] = cvtpk(lo[kk][2], lo[kk][3]);
            a.w[2] = cvtpk(hi[kk][0], hi[kk][1]);
            a.w[3] = cvtpk(hi[kk][2], hi[kk][3]);
            #pragma unroll
            for (int nf = 0; nf < 4; ++nf) {
                int col = wc0 + nf * 16 + lrow;
                int g = kk * 4 + lgrp;
                bf16x8 bv = *(const bf16x8*)&Bp[col * 256 + ((g ^ (col & 7)) << 3)];
                acc[nf] = __builtin_amdgcn_mfma_f32_16x16x32_bf16(a.v, bv, acc[nf], 0, 0, 0);
            }
        }
        #pragma unroll
        for (int nf = 0; nf < 4; ++nf)
            #pragma unroll
            for (int j = 0; j < 4; ++j) {
                int r = t * 16 + lgrp * 4 + j;
                if (r < n) t1[(size_t)r * HID + wc0 + nf * 16 + lrow] = f2b(acc[nf][j]);
            }
    }
}

// ---------------- agg1: out1 = relu(gather(t1) + b1) ------------------------
__global__ __launch_bounds__(256) void k_agg1(
    const unsigned short* __restrict__ t1, const int* __restrict__ rs,
    const int* __restrict__ cnt, const int2* __restrict__ csrw,
    const float* __restrict__ b1, unsigned short* __restrict__ out1, int n) {
    const int w = blockIdx.x * 4 + (threadIdx.x >> 6);
    const int nodeA = w * 2, nodeB = w * 2 + 1;
    if (nodeA >= n) return;
    const bool hasB = (nodeB < n);
    const int lane = threadIdx.x & 63;
    const int ch = lane * 4;
    const int begA = rs[nodeA], mA = cnt[nodeA] + 1;
    int begB = 0, mB = 0;
    if (hasB) { begB = rs[nodeB]; mB = cnt[nodeB] + 1; }
    float a0 = 0.f, a1 = 0.f, a2 = 0.f, a3 = 0.f;
    float c0 = 0.f, c1 = 0.f, c2 = 0.f, c3 = 0.f;
    const int mmax = mA > mB ? mA : mB;
    for (int j = 0; j < mmax; ++j) {
        if (j < mA) {
            int2 p = csrw[begA + j];
            float wA = __int_as_float(p.y);
            u16x4 u = *(const u16x4*)&t1[(size_t)p.x * HID + ch];
            a0 += b2f(u[0]) * wA; a1 += b2f(u[1]) * wA;
            a2 += b2f(u[2]) * wA; a3 += b2f(u[3]) * wA;
        }
        if (j < mB) {
            int2 p = csrw[begB + j];
            float wB = __int_as_float(p.y);
            u16x4 u = *(const u16x4*)&t1[(size_t)p.x * HID + ch];
            c0 += b2f(u[0]) * wB; c1 += b2f(u[1]) * wB;
            c2 += b2f(u[2]) * wB; c3 += b2f(u[3]) * wB;
        }
    }
    float4 bb = *(const float4*)(b1 + ch);
    u16x4 o;
    o[0] = f2b(fmaxf(a0 + bb.x, 0.f));
    o[1] = f2b(fmaxf(a1 + bb.y, 0.f));
    o[2] = f2b(fmaxf(a2 + bb.z, 0.f));
    o[3] = f2b(fmaxf(a3 + bb.w, 0.f));
    *(u16x4*)&out1[(size_t)nodeA * HID + ch] = o;
    if (hasB) {
        u16x4 q;
        q[0] = f2b(fmaxf(c0 + bb.x, 0.f));
        q[1] = f2b(fmaxf(c1 + bb.y, 0.f));
        q[2] = f2b(fmaxf(c2 + bb.z, 0.f));
        q[3] = f2b(fmaxf(c3 + bb.w, 0.f));
        *(u16x4*)&out1[(size_t)nodeB * HID + ch] = q;
    }
}

// ---------------- GEMM2: t2[n][128] bf16 = out1(bf16) @ W2 ------------------
// Same flat structure; panel = 128x256 bf16 = 64 KiB LDS. 16 waves = 8 row-
// streams x 2 col-waves (64 cols each).
__global__ __launch_bounds__(1024) void k_gemm2(
    const unsigned short* __restrict__ out1, const unsigned short* __restrict__ W2T,
    unsigned short* __restrict__ t2, int n, int ntiles) {
    __shared__ __align__(16) unsigned short Bp[128 * 256];   // 64 KiB
    const int tid = threadIdx.x;
    #pragma unroll
    for (int it = 0; it < 4; ++it) {
        int gi = it * 1024 + tid;
        int col = gi >> 5, g = gi & 31;
        u16x8 v = *(const u16x8*)&W2T[col * 256 + g * 8];
        *(u16x8*)&Bp[col * 256 + ((g ^ (col & 7)) << 3)] = v;
    }
    __syncthreads();
    const int wid = tid >> 6, lane = tid & 63;
    const int rg = wid >> 1;
    const int wc0 = (wid & 1) << 6;
    const int lrow = lane & 15, lgrp = lane >> 4;

    for (int t = blockIdx.x * 8 + rg; t < ntiles; t += 4096) {
        int ar = t * 16 + lrow; if (ar >= n) ar = n - 1;
        const unsigned short* ap = out1 + (size_t)ar * HID + lgrp * 8;
        bf16x8 a[8];
        #pragma unroll
        for (int kk = 0; kk < 8; ++kk)
            a[kk] = *(const bf16x8*)(ap + kk * 32);
        f32x4 acc[4];
        #pragma unroll
        for (int nf = 0; nf < 4; ++nf) acc[nf] = (f32x4){0.f, 0.f, 0.f, 0.f};
        #pragma unroll
        for (int kk = 0; kk < 8; ++kk) {
            #pragma unroll
            for (int nf = 0; nf < 4; ++nf) {
                int col = wc0 + nf * 16 + lrow;
                int g = kk * 4 + lgrp;
                bf16x8 bv = *(const bf16x8*)&Bp[col * 256 + ((g ^ (col & 7)) << 3)];
                acc[nf] = __builtin_amdgcn_mfma_f32_16x16x32_bf16(a[kk], bv, acc[nf], 0, 0, 0);
            }
        }
        #pragma unroll
        for (int nf = 0; nf < 4; ++nf)
            #pragma unroll
            for (int j = 0; j < 4; ++j) {
                int r = t * 16 + lgrp * 4 + j;
                if (r < n) t2[(size_t)r * OUT_C + wc0 + nf * 16 + lrow] = f2b(acc[nf][j]);
            }
    }
}

// ---------------- agg2: out(f32) = gather(t2) + b2 --------------------------
__global__ __launch_bounds__(256) void k_agg2(
    const unsigned short* __restrict__ t2, const int* __restrict__ rs,
    const int* __restrict__ cnt, const int2* __restrict__ csrw,
    const float* __restrict__ b2, float* __restrict__ out, int n) {
    const int w = blockIdx.x * 4 + (threadIdx.x >> 6);
    const int nodeA = w * 2, nodeB = w * 2 + 1;
    if (nodeA >= n) return;
    const bool hasB = (nodeB < n);
    const int lane = threadIdx.x & 63;
    const int ch = lane * 2;
    const int begA = rs[nodeA], mA = cnt[nodeA] + 1;
    int begB = 0, mB = 0;
    if (hasB) { begB = rs[nodeB]; mB = cnt[nodeB] + 1; }
    float a0 = 0.f, a1 = 0.f, c0 = 0.f, c1 = 0.f;
    const int mmax = mA > mB ? mA : mB;
    for (int j = 0; j < mmax; ++j) {
        if (j < mA) {
            int2 p = csrw[begA + j];
            float wA = __int_as_float(p.y);
            u16x2 u = *(const u16x2*)&t2[(size_t)p.x * OUT_C + ch];
            a0 += b2f(u[0]) * wA; a1 += b2f(u[1]) * wA;
        }
        if (j < mB) {
            int2 p = csrw[begB + j];
            float wB = __int_as_float(p.y);
            u16x2 u = *(const u16x2*)&t2[(size_t)p.x * OUT_C + ch];
            c0 += b2f(u[0]) * wB; c1 += b2f(u[1]) * wB;
        }
    }
    float2 bb = *(const float2*)(b2 + ch);
    *(float2*)&out[(size_t)nodeA * OUT_C + ch] = make_float2(a0 + bb.x, a1 + bb.y);
    if (hasB)
        *(float2*)&out[(size_t)nodeB * OUT_C + ch] = make_float2(c0 + bb.x, c1 + bb.y);
}

extern "C" void kernel_launch(void* const* d_in, const int* in_sizes, int n_in,
                              void* d_out, int out_size, void* d_ws, size_t ws_size,
                              hipStream_t stream) {
    const float* x  = (const float*)d_in[0];
    const int*   ei = (const int*)d_in[1];
    const float* W1 = (const float*)d_in[2];
    const float* b1 = (const float*)d_in[3];
    const float* W2 = (const float*)d_in[4];
    const float* b2 = (const float*)d_in[5];
    float* out = (float*)d_out;

    const int n = in_sizes[0] / IN_C;   // 100000
    const int e = in_sizes[1] / 2;      // 300000
    const int* src = ei;
    const int* dst = ei + e;

    // workspace layout (4B words; csrw 8B-aligned, t1 16B-aligned)
    int*   cnt  = (int*)d_ws;                       // [n]
    int*   rs   = cnt + n;                          // [n]
    int*   cur  = rs + n;                           // [n]
    int*   bsum = cur + n;                          // [128]
    float* dinv = (float*)(bsum + 128);             // [n]
    int2*  csrw = (int2*)(dinv + n);                // [e+n] pairs {src, weight}
    unsigned short* W1T = (unsigned short*)(csrw + (size_t)e + n);  // [256*256]
    unsigned short* W2T = W1T + 65536;                              // [128*256]
    unsigned short* t1  = W2T + 32768;                              // [n*HID]
    unsigned short* out1 = t1 + (size_t)n * HID;                    // [n*HID]
    unsigned short* t2  = t1;                                       // alias

    const int nb = (n + SCAN_BS - 1) / SCAN_BS;

    k_zero_i<<<(n + 255) / 256, 256, 0, stream>>>(cnt, n);
    k_count<<<(e + 255) / 256, 256, 0, stream>>>(dst, cnt, e);
    k_scan_block<<<nb, SCAN_BS, 0, stream>>>(cnt, rs, bsum, n);
    k_scan_sums<<<1, 128, 0, stream>>>(bsum, nb);
    k_scan_add<<<(n + 255) / 256, 256, 0, stream>>>(rs, cur, bsum, cnt, dinv, csrw, n);
    k_fill<<<(e + 255) / 256, 256, 0, stream>>>(src, dst, dinv, cur, csrw, e);
    k_prep<<<256, 256, 0, stream>>>(W1, W2, W1T, W2T);

    const int ntiles = (n + 15) / 16;   // 6250
    k_gemm1<<<256, 1024, 0, stream>>>(x, W1T, t1, n, ntiles);
    const int aggblk = (n + 7) / 8;
    k_agg1<<<aggblk, 256, 0, stream>>>(t1, rs, cnt, csrw, b1, out1, n);
    k_gemm2<<<512, 1024, 0, stream>>>(out1, W2T, t2, n, ntiles);
    k_agg2<<<aggblk, 256, 0, stream>>>(t2, rs, cnt, csrw, b2, out, n);
}

// Round 9
// 216.418 us; speedup vs baseline: 1.2474x; 1.2474x over previous
//
#include <hip/hip_runtime.h>
#include <stdint.h>

#define IN_C  256
#define HID   256
#define OUT_C 128
#define SCAN_BS 1024

typedef __bf16 bf16x8 __attribute__((ext_vector_type(8)));
typedef float  f32x4  __attribute__((ext_vector_type(4)));
typedef unsigned short u16x8 __attribute__((ext_vector_type(8)));
typedef unsigned short u16x4 __attribute__((ext_vector_type(4)));
typedef unsigned short u16x2 __attribute__((ext_vector_type(2)));

static __device__ __forceinline__ unsigned short f2b(float f) {
    union { float f; uint32_t u; } v; v.f = f;
    uint32_t r = v.u + 0x7fffu + ((v.u >> 16) & 1u);
    return (unsigned short)(r >> 16);
}
static __device__ __forceinline__ float b2f(unsigned short b) {
    union { uint32_t u; float f; } v; v.u = ((uint32_t)b) << 16;
    return v.f;
}

// ---------------- CSR build (self-loop folded in; per-edge weight precomputed) ----
__global__ void k_zero_i(int* __restrict__ p, int n) {
    int i = blockIdx.x * blockDim.x + threadIdx.x;
    if (i < n) p[i] = 0;
}

__global__ void k_count(const int* __restrict__ dst, int* __restrict__ cnt, int e) {
    int i = blockIdx.x * blockDim.x + threadIdx.x;
    if (i < e) atomicAdd(&cnt[dst[i]], 1);
}

__global__ __launch_bounds__(SCAN_BS) void k_scan_block(
    const int* __restrict__ cnt, int* __restrict__ rs, int* __restrict__ bsum, int n) {
    __shared__ int s[SCAN_BS];
    const int tid = threadIdx.x;
    const int i = blockIdx.x * SCAN_BS + tid;
    int v = (i < n) ? cnt[i] + 1 : 0;
    s[tid] = v;
    __syncthreads();
    for (int off = 1; off < SCAN_BS; off <<= 1) {
        int t = (tid >= off) ? s[tid - off] : 0;
        __syncthreads();
        s[tid] += t;
        __syncthreads();
    }
    if (i < n) rs[i] = s[tid] - v;
    if (tid == SCAN_BS - 1) bsum[blockIdx.x] = s[tid];
}

__global__ void k_scan_sums(int* __restrict__ bsum, int nb) {
    __shared__ int s[128];
    const int tid = threadIdx.x;
    int v = (tid < nb) ? bsum[tid] : 0;
    s[tid] = v;
    __syncthreads();
    for (int off = 1; off < 128; off <<= 1) {
        int t = (tid >= off) ? s[tid - off] : 0;
        __syncthreads();
        s[tid] += t;
        __syncthreads();
    }
    if (tid < nb) bsum[tid] = s[tid] - v;
}

__global__ void k_scan_add(int* __restrict__ rs, int* __restrict__ cur,
                           const int* __restrict__ bsum, const int* __restrict__ cnt,
                           float* __restrict__ dinv, int2* __restrict__ csrw, int n) {
    int i = blockIdx.x * blockDim.x + threadIdx.x;
    if (i < n) {
        int v = rs[i] + bsum[i >> 10];
        rs[i] = v;
        cur[i] = v + 1;
        float dp1 = (float)(cnt[i] + 1);
        dinv[i] = rsqrtf(dp1);
        csrw[v] = make_int2(i, __float_as_int(1.0f / dp1));   // self: weight = dinv^2
    }
}

__global__ void k_fill(const int* __restrict__ src, const int* __restrict__ dst,
                       const float* __restrict__ dinv,
                       int* __restrict__ cur, int2* __restrict__ csrw, int e) {
    int i = blockIdx.x * blockDim.x + threadIdx.x;
    if (i < e) {
        int s = src[i], d = dst[i];
        int p = atomicAdd(&cur[d], 1);
        csrw[p] = make_int2(s, __float_as_int(dinv[s] * dinv[d]));
    }
}

__global__ void k_prep(const float* __restrict__ W1, const float* __restrict__ W2,
                       unsigned short* __restrict__ W1T, unsigned short* __restrict__ W2T) {
    int i = blockIdx.x * blockDim.x + threadIdx.x;
    if (i < 65536) W1T[i] = f2b(W1[(i & 255) * HID + (i >> 8)]);
    if (i < 32768) W2T[i] = f2b(W2[(i & 255) * OUT_C + (i >> 8)]);
}

// ---------------- GEMM1 (R5-proven): t1[n][256] bf16 = x(f32->bf16) @ W1 ----
// BM=128, BN=256 (full), BK=64. 512 threads = 8 waves (2x4), wave tile 64x64.
__global__ __launch_bounds__(512) void k_gemm1(
    const float* __restrict__ x, const unsigned short* __restrict__ W1T,
    unsigned short* __restrict__ t1, int n) {
    __shared__ __align__(16) unsigned short As[128 * 64];
    __shared__ __align__(16) unsigned short Bs[256 * 64];
    const int tid  = threadIdx.x;
    const int row0 = blockIdx.x * 128;
    const int wid = tid >> 6, lane = tid & 63;
    const int wm = wid >> 2, wn = wid & 3;
    const int lrow = lane & 15, lgrp = lane >> 4;

    f32x4 acc[4][4];
    #pragma unroll
    for (int i = 0; i < 4; ++i)
        #pragma unroll
        for (int j = 0; j < 4; ++j)
            acc[i][j] = (f32x4){0.f, 0.f, 0.f, 0.f};

    for (int kt = 0; kt < 4; ++kt) {
        #pragma unroll
        for (int i = 0; i < 2; ++i) {
            int chunk = tid + 512 * i;
            int r = chunk >> 3, c = chunk & 7;
            int grow = row0 + r;
            u16x8 pk = {0, 0, 0, 0, 0, 0, 0, 0};
            if (grow < n) {
                const float* sp = x + (size_t)grow * IN_C + kt * 64 + c * 8;
                float4 a = *(const float4*)sp;
                float4 b = *(const float4*)(sp + 4);
                pk[0] = f2b(a.x); pk[1] = f2b(a.y); pk[2] = f2b(a.z); pk[3] = f2b(a.w);
                pk[4] = f2b(b.x); pk[5] = f2b(b.y); pk[6] = f2b(b.z); pk[7] = f2b(b.w);
            }
            *(u16x8*)&As[r * 64 + ((c ^ (r & 7)) * 8)] = pk;
        }
        #pragma unroll
        for (int i = 0; i < 4; ++i) {
            int chunk = tid + 512 * i;
            int nn = chunk >> 3, c = chunk & 7;
            u16x8 pk = *(const u16x8*)&W1T[(size_t)nn * 256 + kt * 64 + c * 8];
            *(u16x8*)&Bs[nn * 64 + ((c ^ (nn & 7)) * 8)] = pk;
        }
        __syncthreads();
        #pragma unroll
        for (int kk = 0; kk < 2; ++kk) {
            const int cfrag = kk * 4 + lgrp;
            bf16x8 av[4], bv[4];
            #pragma unroll
            for (int mf = 0; mf < 4; ++mf) {
                int r = wm * 64 + mf * 16 + lrow;
                av[mf] = *(const bf16x8*)&As[r * 64 + ((cfrag ^ (r & 7)) * 8)];
            }
            #pragma unroll
            for (int nf = 0; nf < 4; ++nf) {
                int cc = wn * 64 + nf * 16 + lrow;
                bv[nf] = *(const bf16x8*)&Bs[cc * 64 + ((cfrag ^ (cc & 7)) * 8)];
            }
            #pragma unroll
            for (int mf = 0; mf < 4; ++mf)
                #pragma unroll
                for (int nf = 0; nf < 4; ++nf)
                    acc[mf][nf] = __builtin_amdgcn_mfma_f32_16x16x32_bf16(
                        av[mf], bv[nf], acc[mf][nf], 0, 0, 0);
        }
        __syncthreads();
    }
    #pragma unroll
    for (int mf = 0; mf < 4; ++mf)
        #pragma unroll
        for (int j = 0; j < 4; ++j) {
            int grow = row0 + wm * 64 + mf * 16 + lgrp * 4 + j;
            if (grow < n) {
                #pragma unroll
                for (int nf = 0; nf < 4; ++nf) {
                    int col = wn * 64 + nf * 16 + lrow;
                    t1[(size_t)grow * HID + col] = f2b(acc[mf][nf][j]);
                }
            }
        }
}

// ---------------- agg1: out1 = relu(gather(t1) + b1) ------------------------
// 4 nodes per wave (4 independent gather chains for MLP); uniform pair loop
// (self-loop is CSR slot 0). Branches on j<m[q] are wave-uniform.
__global__ __launch_bounds__(256) void k_agg1(
    const unsigned short* __restrict__ t1, const int* __restrict__ rs,
    const int* __restrict__ cnt, const int2* __restrict__ csrw,
    const float* __restrict__ b1, unsigned short* __restrict__ out1, int n) {
    const int w = blockIdx.x * 4 + (threadIdx.x >> 6);
    const int n0 = w * 4;
    if (n0 >= n) return;
    const int lane = threadIdx.x & 63;
    const int ch = lane * 4;
    int beg[4], m[4];
    #pragma unroll
    for (int q = 0; q < 4; ++q) {
        int node = n0 + q;
        bool valid = node < n;
        beg[q] = valid ? rs[node] : 0;
        m[q]   = valid ? cnt[node] + 1 : 0;
    }
    float acc[4][4];
    #pragma unroll
    for (int q = 0; q < 4; ++q)
        #pragma unroll
        for (int k = 0; k < 4; ++k) acc[q][k] = 0.f;
    const int m01 = m[0] > m[1] ? m[0] : m[1];
    const int m23 = m[2] > m[3] ? m[2] : m[3];
    const int mmax = m01 > m23 ? m01 : m23;
    for (int j = 0; j < mmax; ++j) {
        #pragma unroll
        for (int q = 0; q < 4; ++q) {
            if (j < m[q]) {
                int2 p = csrw[beg[q] + j];
                float wq = __int_as_float(p.y);
                u16x4 u = *(const u16x4*)&t1[(size_t)p.x * HID + ch];
                acc[q][0] += b2f(u[0]) * wq; acc[q][1] += b2f(u[1]) * wq;
                acc[q][2] += b2f(u[2]) * wq; acc[q][3] += b2f(u[3]) * wq;
            }
        }
    }
    float4 bb = *(const float4*)(b1 + ch);
    #pragma unroll
    for (int q = 0; q < 4; ++q) {
        int node = n0 + q;
        if (node < n) {
            u16x4 o;
            o[0] = f2b(fmaxf(acc[q][0] + bb.x, 0.f));
            o[1] = f2b(fmaxf(acc[q][1] + bb.y, 0.f));
            o[2] = f2b(fmaxf(acc[q][2] + bb.z, 0.f));
            o[3] = f2b(fmaxf(acc[q][3] + bb.w, 0.f));
            *(u16x4*)&out1[(size_t)node * HID + ch] = o;
        }
    }
}

// ---------------- GEMM2 (R5-proven): t2[n][128] bf16 = out1(bf16) @ W2 ------
// BM=128, BN=128, BK=64. 256 threads = 4 waves (2x2), wave tile 64x64.
__global__ __launch_bounds__(256) void k_gemm2(
    const unsigned short* __restrict__ out1, const unsigned short* __restrict__ W2T,
    unsigned short* __restrict__ t2, int n) {
    __shared__ __align__(16) unsigned short As[128 * 64];
    __shared__ __align__(16) unsigned short Bs[128 * 64];
    const int tid  = threadIdx.x;
    const int row0 = blockIdx.x * 128;
    const int wid = tid >> 6, lane = tid & 63;
    const int wm = wid >> 1, wn = wid & 1;
    const int lrow = lane & 15, lgrp = lane >> 4;

    f32x4 acc[4][4];
    #pragma unroll
    for (int i = 0; i < 4; ++i)
        #pragma unroll
        for (int j = 0; j < 4; ++j)
            acc[i][j] = (f32x4){0.f, 0.f, 0.f, 0.f};

    for (int kt = 0; kt < 4; ++kt) {
        #pragma unroll
        for (int i = 0; i < 4; ++i) {
            int chunk = tid + 256 * i;
            int r = chunk >> 3, c = chunk & 7;
            int grow = row0 + r;
            u16x8 pk = {0, 0, 0, 0, 0, 0, 0, 0};
            if (grow < n)
                pk = *(const u16x8*)&out1[(size_t)grow * HID + kt * 64 + c * 8];
            *(u16x8*)&As[r * 64 + ((c ^ (r & 7)) * 8)] = pk;
        }
        #pragma unroll
        for (int i = 0; i < 4; ++i) {
            int chunk = tid + 256 * i;
            int nn = chunk >> 3, c = chunk & 7;
            u16x8 pk = *(const u16x8*)&W2T[(size_t)nn * 256 + kt * 64 + c * 8];
            *(u16x8*)&Bs[nn * 64 + ((c ^ (nn & 7)) * 8)] = pk;
        }
        __syncthreads();
        #pragma unroll
        for (int kk = 0; kk < 2; ++kk) {
            const int cfrag = kk * 4 + lgrp;
            bf16x8 av[4], bv[4];
            #pragma unroll
            for (int mf = 0; mf < 4; ++mf) {
                int r = wm * 64 + mf * 16 + lrow;
                av[mf] = *(const bf16x8*)&As[r * 64 + ((cfrag ^ (r & 7)) * 8)];
            }
            #pragma unroll
            for (int nf = 0; nf < 4; ++nf) {
                int cc = wn * 64 + nf * 16 + lrow;
                bv[nf] = *(const bf16x8*)&Bs[cc * 64 + ((cfrag ^ (cc & 7)) * 8)];
            }
            #pragma unroll
            for (int mf = 0; mf < 4; ++mf)
                #pragma unroll
                for (int nf = 0; nf < 4; ++nf)
                    acc[mf][nf] = __builtin_amdgcn_mfma_f32_16x16x32_bf16(
                        av[mf], bv[nf], acc[mf][nf], 0, 0, 0);
        }
        __syncthreads();
    }
    #pragma unroll
    for (int mf = 0; mf < 4; ++mf)
        #pragma unroll
        for (int j = 0; j < 4; ++j) {
            int grow = row0 + wm * 64 + mf * 16 + lgrp * 4 + j;
            if (grow < n) {
                #pragma unroll
                for (int nf = 0; nf < 4; ++nf) {
                    int col = wn * 64 + nf * 16 + lrow;
                    t2[(size_t)grow * OUT_C + col] = f2b(acc[mf][nf][j]);
                }
            }
        }
}

// ---------------- agg2: out(f32) = gather(t2) + b2 --------------------------
// 4 nodes per wave, u16x2 per lane per node.
__global__ __launch_bounds__(256) void k_agg2(
    const unsigned short* __restrict__ t2, const int* __restrict__ rs,
    const int* __restrict__ cnt, const int2* __restrict__ csrw,
    const float* __restrict__ b2, float* __restrict__ out, int n) {
    const int w = blockIdx.x * 4 + (threadIdx.x >> 6);
    const int n0 = w * 4;
    if (n0 >= n) return;
    const int lane = threadIdx.x & 63;
    const int ch = lane * 2;
    int beg[4], m[4];
    #pragma unroll
    for (int q = 0; q < 4; ++q) {
        int node = n0 + q;
        bool valid = node < n;
        beg[q] = valid ? rs[node] : 0;
        m[q]   = valid ? cnt[node] + 1 : 0;
    }
    float acc[4][2];
    #pragma unroll
    for (int q = 0; q < 4; ++q) { acc[q][0] = 0.f; acc[q][1] = 0.f; }
    const int m01 = m[0] > m[1] ? m[0] : m[1];
    const int m23 = m[2] > m[3] ? m[2] : m[3];
    const int mmax = m01 > m23 ? m01 : m23;
    for (int j = 0; j < mmax; ++j) {
        #pragma unroll
        for (int q = 0; q < 4; ++q) {
            if (j < m[q]) {
                int2 p = csrw[beg[q] + j];
                float wq = __int_as_float(p.y);
                u16x2 u = *(const u16x2*)&t2[(size_t)p.x * OUT_C + ch];
                acc[q][0] += b2f(u[0]) * wq; acc[q][1] += b2f(u[1]) * wq;
            }
        }
    }
    float2 bb = *(const float2*)(b2 + ch);
    #pragma unroll
    for (int q = 0; q < 4; ++q) {
        int node = n0 + q;
        if (node < n)
            *(float2*)&out[(size_t)node * OUT_C + ch] =
                make_float2(acc[q][0] + bb.x, acc[q][1] + bb.y);
    }
}

extern "C" void kernel_launch(void* const* d_in, const int* in_sizes, int n_in,
                              void* d_out, int out_size, void* d_ws, size_t ws_size,
                              hipStream_t stream) {
    const float* x  = (const float*)d_in[0];
    const int*   ei = (const int*)d_in[1];
    const float* W1 = (const float*)d_in[2];
    const float* b1 = (const float*)d_in[3];
    const float* W2 = (const float*)d_in[4];
    const float* b2 = (const float*)d_in[5];
    float* out = (float*)d_out;

    const int n = in_sizes[0] / IN_C;   // 100000
    const int e = in_sizes[1] / 2;      // 300000
    const int* src = ei;
    const int* dst = ei + e;

    // workspace layout (4B words; csrw 8B-aligned, t1 16B-aligned)
    int*   cnt  = (int*)d_ws;                       // [n]
    int*   rs   = cnt + n;                          // [n]
    int*   cur  = rs + n;                           // [n]
    int*   bsum = cur + n;                          // [128]
    float* dinv = (float*)(bsum + 128);             // [n]
    int2*  csrw = (int2*)(dinv + n);                // [e+n] pairs {src, weight}
    unsigned short* W1T = (unsigned short*)(csrw + (size_t)e + n);  // [256*256]
    unsigned short* W2T = W1T + 65536;                              // [128*256]
    unsigned short* t1  = W2T + 32768;                              // [n*HID]
    unsigned short* out1 = t1 + (size_t)n * HID;                    // [n*HID]
    unsigned short* t2  = t1;                                       // alias

    const int nb = (n + SCAN_BS - 1) / SCAN_BS;

    k_zero_i<<<(n + 255) / 256, 256, 0, stream>>>(cnt, n);
    k_count<<<(e + 255) / 256, 256, 0, stream>>>(dst, cnt, e);
    k_scan_block<<<nb, SCAN_BS, 0, stream>>>(cnt, rs, bsum, n);
    k_scan_sums<<<1, 128, 0, stream>>>(bsum, nb);
    k_scan_add<<<(n + 255) / 256, 256, 0, stream>>>(rs, cur, bsum, cnt, dinv, csrw, n);
    k_fill<<<(e + 255) / 256, 256, 0, stream>>>(src, dst, dinv, cur, csrw, e);
    k_prep<<<256, 256, 0, stream>>>(W1, W2, W1T, W2T);

    const int mb = (n + 127) / 128;   // 782
    k_gemm1<<<mb, 512, 0, stream>>>(x, W1T, t1, n);
    const int aggblk = (n + 15) / 16;   // 16 nodes per block (4 waves x 4)
    k_agg1<<<aggblk, 256, 0, stream>>>(t1, rs, cnt, csrw, b1, out1, n);
    k_gemm2<<<mb, 256, 0, stream>>>(out1, W2T, t2, n);
    k_agg2<<<aggblk, 256, 0, stream>>>(t2, rs, cnt, csrw, b2, out, n);
}

// Round 10
// 208.779 us; speedup vs baseline: 1.2930x; 1.0366x over previous
//
#include <hip/hip_runtime.h>
#include <stdint.h>

#define IN_C  256
#define HID   256
#define OUT_C 128
#define SCAN_BS 1024

typedef __bf16 bf16x8 __attribute__((ext_vector_type(8)));
typedef float  f32x4  __attribute__((ext_vector_type(4)));
typedef unsigned short u16x8 __attribute__((ext_vector_type(8)));
typedef unsigned short u16x4 __attribute__((ext_vector_type(4)));
typedef unsigned short u16x2 __attribute__((ext_vector_type(2)));
typedef unsigned int u32;

static __device__ __forceinline__ unsigned short f2b(float f) {
    union { float f; uint32_t u; } v; v.f = f;
    uint32_t r = v.u + 0x7fffu + ((v.u >> 16) & 1u);
    return (unsigned short)(r >> 16);
}
static __device__ __forceinline__ float b2f(unsigned short b) {
    union { uint32_t u; float f; } v; v.u = ((uint32_t)b) << 16;
    return v.f;
}

// async global->LDS, 16B per lane; dest must be wave-uniform base + lane*16
typedef __attribute__((address_space(1))) const u32 gas_u32;
typedef __attribute__((address_space(3))) u32 las_u32;
static __device__ __forceinline__ void gld16(const void* g, void* l) {
    __builtin_amdgcn_global_load_lds((gas_u32*)g, (las_u32*)l, 16, 0, 0);
}

// ---------------- CSR build (self-loop folded in; per-edge weight precomputed) ----
__global__ void k_zero_i(int* __restrict__ p, int n) {
    int i = blockIdx.x * blockDim.x + threadIdx.x;
    if (i < n) p[i] = 0;
}

__global__ void k_count(const int* __restrict__ dst, int* __restrict__ cnt, int e) {
    int i = blockIdx.x * blockDim.x + threadIdx.x;
    if (i < e) atomicAdd(&cnt[dst[i]], 1);
}

__global__ __launch_bounds__(SCAN_BS) void k_scan_block(
    const int* __restrict__ cnt, int* __restrict__ rs, int* __restrict__ bsum, int n) {
    __shared__ int s[SCAN_BS];
    const int tid = threadIdx.x;
    const int i = blockIdx.x * SCAN_BS + tid;
    int v = (i < n) ? cnt[i] + 1 : 0;
    s[tid] = v;
    __syncthreads();
    for (int off = 1; off < SCAN_BS; off <<= 1) {
        int t = (tid >= off) ? s[tid - off] : 0;
        __syncthreads();
        s[tid] += t;
        __syncthreads();
    }
    if (i < n) rs[i] = s[tid] - v;
    if (tid == SCAN_BS - 1) bsum[blockIdx.x] = s[tid];
}

__global__ void k_scan_sums(int* __restrict__ bsum, int nb) {
    __shared__ int s[128];
    const int tid = threadIdx.x;
    int v = (tid < nb) ? bsum[tid] : 0;
    s[tid] = v;
    __syncthreads();
    for (int off = 1; off < 128; off <<= 1) {
        int t = (tid >= off) ? s[tid - off] : 0;
        __syncthreads();
        s[tid] += t;
        __syncthreads();
    }
    if (tid < nb) bsum[tid] = s[tid] - v;
}

__global__ void k_scan_add(int* __restrict__ rs, int* __restrict__ cur,
                           const int* __restrict__ bsum, const int* __restrict__ cnt,
                           float* __restrict__ dinv, int2* __restrict__ csrw, int n) {
    int i = blockIdx.x * blockDim.x + threadIdx.x;
    if (i < n) {
        int v = rs[i] + bsum[i >> 10];
        rs[i] = v;
        cur[i] = v + 1;
        float dp1 = (float)(cnt[i] + 1);
        dinv[i] = rsqrtf(dp1);
        csrw[v] = make_int2(i, __float_as_int(1.0f / dp1));   // self: weight = dinv^2
    }
}

__global__ void k_fill(const int* __restrict__ src, const int* __restrict__ dst,
                       const float* __restrict__ dinv,
                       int* __restrict__ cur, int2* __restrict__ csrw, int e) {
    int i = blockIdx.x * blockDim.x + threadIdx.x;
    if (i < e) {
        int s = src[i], d = dst[i];
        int p = atomicAdd(&cur[d], 1);
        csrw[p] = make_int2(s, __float_as_int(dinv[s] * dinv[d]));
    }
}

__global__ void k_prep(const float* __restrict__ W1, const float* __restrict__ W2,
                       unsigned short* __restrict__ W1T, unsigned short* __restrict__ W2T) {
    int i = blockIdx.x * blockDim.x + threadIdx.x;
    if (i < 65536) W1T[i] = f2b(W1[(i & 255) * HID + (i >> 8)]);
    if (i < 32768) W2T[i] = f2b(W2[(i & 255) * OUT_C + (i >> 8)]);
}

// ---------------- GEMM1: t1[n][256] bf16 = x(f32->bf16) @ W1 ----------------
// R5 geometry (BM=128, BN=256, BK=64, 512 thr = 8 waves 2x4, LDS layout
// byte-identical). Change: B staged via global_load_lds width-16 with
// inverse-swizzled global source (rule #21); A keeps register f2b path.
__global__ __launch_bounds__(512) void k_gemm1(
    const float* __restrict__ x, const unsigned short* __restrict__ W1T,
    unsigned short* __restrict__ t1, int n) {
    __shared__ __align__(16) unsigned short As[128 * 64];
    __shared__ __align__(16) unsigned short Bs[256 * 64];
    const int tid  = threadIdx.x;
    const int row0 = blockIdx.x * 128;
    const int wid = tid >> 6, lane = tid & 63;
    const int wm = wid >> 2, wn = wid & 3;
    const int lrow = lane & 15, lgrp = lane >> 4;

    f32x4 acc[4][4];
    #pragma unroll
    for (int i = 0; i < 4; ++i)
        #pragma unroll
        for (int j = 0; j < 4; ++j)
            acc[i][j] = (f32x4){0.f, 0.f, 0.f, 0.f};

    for (int kt = 0; kt < 4; ++kt) {
        // B: async copy. LDS slot (nn, c) must hold global granule (c ^ (nn&7))
        // so that the R5 read Bs[nn*64 + ((cfrag^(nn&7))*8)] sees granule cfrag.
        // Dest is linear: Bs + chunk*8 elems = wave-uniform base + lane*16B.
        #pragma unroll
        for (int i = 0; i < 4; ++i) {
            int chunk = tid + 512 * i;
            int nn = chunk >> 3, c = chunk & 7;
            gld16(&W1T[(size_t)nn * 256 + kt * 64 + ((c ^ (nn & 7)) * 8)],
                  &Bs[chunk * 8]);
        }
        // A: f32 -> bf16 register staging (conversion requires the roundtrip)
        #pragma unroll
        for (int i = 0; i < 2; ++i) {
            int chunk = tid + 512 * i;
            int r = chunk >> 3, c = chunk & 7;
            int grow = row0 + r;
            u16x8 pk = {0, 0, 0, 0, 0, 0, 0, 0};
            if (grow < n) {
                const float* sp = x + (size_t)grow * IN_C + kt * 64 + c * 8;
                float4 a = *(const float4*)sp;
                float4 b = *(const float4*)(sp + 4);
                pk[0] = f2b(a.x); pk[1] = f2b(a.y); pk[2] = f2b(a.z); pk[3] = f2b(a.w);
                pk[4] = f2b(b.x); pk[5] = f2b(b.y); pk[6] = f2b(b.z); pk[7] = f2b(b.w);
            }
            *(u16x8*)&As[r * 64 + ((c ^ (r & 7)) * 8)] = pk;
        }
        __syncthreads();
        #pragma unroll
        for (int kk = 0; kk < 2; ++kk) {
            const int cfrag = kk * 4 + lgrp;
            bf16x8 av[4], bv[4];
            #pragma unroll
            for (int mf = 0; mf < 4; ++mf) {
                int r = wm * 64 + mf * 16 + lrow;
                av[mf] = *(const bf16x8*)&As[r * 64 + ((cfrag ^ (r & 7)) * 8)];
            }
            #pragma unroll
            for (int nf = 0; nf < 4; ++nf) {
                int cc = wn * 64 + nf * 16 + lrow;
                bv[nf] = *(const bf16x8*)&Bs[cc * 64 + ((cfrag ^ (cc & 7)) * 8)];
            }
            #pragma unroll
            for (int mf = 0; mf < 4; ++mf)
                #pragma unroll
                for (int nf = 0; nf < 4; ++nf)
                    acc[mf][nf] = __builtin_amdgcn_mfma_f32_16x16x32_bf16(
                        av[mf], bv[nf], acc[mf][nf], 0, 0, 0);
        }
        __syncthreads();
    }
    #pragma unroll
    for (int mf = 0; mf < 4; ++mf)
        #pragma unroll
        for (int j = 0; j < 4; ++j) {
            int grow = row0 + wm * 64 + mf * 16 + lgrp * 4 + j;
            if (grow < n) {
                #pragma unroll
                for (int nf = 0; nf < 4; ++nf) {
                    int col = wn * 64 + nf * 16 + lrow;
                    t1[(size_t)grow * HID + col] = f2b(acc[mf][nf][j]);
                }
            }
        }
}

// ---------------- agg1: out1 = relu(gather(t1) + b1) ------------------------
__global__ __launch_bounds__(256) void k_agg1(
    const unsigned short* __restrict__ t1, const int* __restrict__ rs,
    const int* __restrict__ cnt, const int2* __restrict__ csrw,
    const float* __restrict__ b1, unsigned short* __restrict__ out1, int n) {
    const int w = blockIdx.x * 4 + (threadIdx.x >> 6);
    const int n0 = w * 4;
    if (n0 >= n) return;
    const int lane = threadIdx.x & 63;
    const int ch = lane * 4;
    int beg[4], m[4];
    #pragma unroll
    for (int q = 0; q < 4; ++q) {
        int node = n0 + q;
        bool valid = node < n;
        beg[q] = valid ? rs[node] : 0;
        m[q]   = valid ? cnt[node] + 1 : 0;
    }
    float acc[4][4];
    #pragma unroll
    for (int q = 0; q < 4; ++q)
        #pragma unroll
        for (int k = 0; k < 4; ++k) acc[q][k] = 0.f;
    const int m01 = m[0] > m[1] ? m[0] : m[1];
    const int m23 = m[2] > m[3] ? m[2] : m[3];
    const int mmax = m01 > m23 ? m01 : m23;
    for (int j = 0; j < mmax; ++j) {
        #pragma unroll
        for (int q = 0; q < 4; ++q) {
            if (j < m[q]) {
                int2 p = csrw[beg[q] + j];
                float wq = __int_as_float(p.y);
                u16x4 u = *(const u16x4*)&t1[(size_t)p.x * HID + ch];
                acc[q][0] += b2f(u[0]) * wq; acc[q][1] += b2f(u[1]) * wq;
                acc[q][2] += b2f(u[2]) * wq; acc[q][3] += b2f(u[3]) * wq;
            }
        }
    }
    float4 bb = *(const float4*)(b1 + ch);
    #pragma unroll
    for (int q = 0; q < 4; ++q) {
        int node = n0 + q;
        if (node < n) {
            u16x4 o;
            o[0] = f2b(fmaxf(acc[q][0] + bb.x, 0.f));
            o[1] = f2b(fmaxf(acc[q][1] + bb.y, 0.f));
            o[2] = f2b(fmaxf(acc[q][2] + bb.z, 0.f));
            o[3] = f2b(fmaxf(acc[q][3] + bb.w, 0.f));
            *(u16x4*)&out1[(size_t)node * HID + ch] = o;
        }
    }
}

// ---------------- GEMM2: t2[n][128] bf16 = out1(bf16) @ W2 ------------------
// R5 geometry (BM=128, BN=128, BK=64, 256 thr = 4 waves 2x2). Both A and B
// are pure bf16 copies -> both staged via global_load_lds (inverse-swizzled
// source, linear dest; LDS content byte-identical to R5). Boundary rows
// clamped (garbage only reaches discarded C rows).
__global__ __launch_bounds__(256) void k_gemm2(
    const unsigned short* __restrict__ out1, const unsigned short* __restrict__ W2T,
    unsigned short* __restrict__ t2, int n) {
    __shared__ __align__(16) unsigned short As[128 * 64];
    __shared__ __align__(16) unsigned short Bs[128 * 64];
    const int tid  = threadIdx.x;
    const int row0 = blockIdx.x * 128;
    const int wid = tid >> 6, lane = tid & 63;
    const int wm = wid >> 1, wn = wid & 1;
    const int lrow = lane & 15, lgrp = lane >> 4;

    f32x4 acc[4][4];
    #pragma unroll
    for (int i = 0; i < 4; ++i)
        #pragma unroll
        for (int j = 0; j < 4; ++j)
            acc[i][j] = (f32x4){0.f, 0.f, 0.f, 0.f};

    for (int kt = 0; kt < 4; ++kt) {
        #pragma unroll
        for (int i = 0; i < 4; ++i) {
            int chunk = tid + 256 * i;
            int r = chunk >> 3, c = chunk & 7;
            int grow = row0 + r; if (grow > n - 1) grow = n - 1;
            gld16(&out1[(size_t)grow * HID + kt * 64 + ((c ^ (r & 7)) * 8)],
                  &As[chunk * 8]);
        }
        #pragma unroll
        for (int i = 0; i < 4; ++i) {
            int chunk = tid + 256 * i;
            int nn = chunk >> 3, c = chunk & 7;
            gld16(&W2T[(size_t)nn * 256 + kt * 64 + ((c ^ (nn & 7)) * 8)],
                  &Bs[chunk * 8]);
        }
        __syncthreads();
        #pragma unroll
        for (int kk = 0; kk < 2; ++kk) {
            const int cfrag = kk * 4 + lgrp;
            bf16x8 av[4], bv[4];
            #pragma unroll
            for (int mf = 0; mf < 4; ++mf) {
                int r = wm * 64 + mf * 16 + lrow;
                av[mf] = *(const bf16x8*)&As[r * 64 + ((cfrag ^ (r & 7)) * 8)];
            }
            #pragma unroll
            for (int nf = 0; nf < 4; ++nf) {
                int cc = wn * 64 + nf * 16 + lrow;
                bv[nf] = *(const bf16x8*)&Bs[cc * 64 + ((cfrag ^ (cc & 7)) * 8)];
            }
            #pragma unroll
            for (int mf = 0; mf < 4; ++mf)
                #pragma unroll
                for (int nf = 0; nf < 4; ++nf)
                    acc[mf][nf] = __builtin_amdgcn_mfma_f32_16x16x32_bf16(
                        av[mf], bv[nf], acc[mf][nf], 0, 0, 0);
        }
        __syncthreads();
    }
    #pragma unroll
    for (int mf = 0; mf < 4; ++mf)
        #pragma unroll
        for (int j = 0; j < 4; ++j) {
            int grow = row0 + wm * 64 + mf * 16 + lgrp * 4 + j;
            if (grow < n) {
                #pragma unroll
                for (int nf = 0; nf < 4; ++nf) {
                    int col = wn * 64 + nf * 16 + lrow;
                    t2[(size_t)grow * OUT_C + col] = f2b(acc[mf][nf][j]);
                }
            }
        }
}

// ---------------- agg2: out(f32) = gather(t2) + b2 --------------------------
__global__ __launch_bounds__(256) void k_agg2(
    const unsigned short* __restrict__ t2, const int* __restrict__ rs,
    const int* __restrict__ cnt, const int2* __restrict__ csrw,
    const float* __restrict__ b2, float* __restrict__ out, int n) {
    const int w = blockIdx.x * 4 + (threadIdx.x >> 6);
    const int n0 = w * 4;
    if (n0 >= n) return;
    const int lane = threadIdx.x & 63;
    const int ch = lane * 2;
    int beg[4], m[4];
    #pragma unroll
    for (int q = 0; q < 4; ++q) {
        int node = n0 + q;
        bool valid = node < n;
        beg[q] = valid ? rs[node] : 0;
        m[q]   = valid ? cnt[node] + 1 : 0;
    }
    float acc[4][2];
    #pragma unroll
    for (int q = 0; q < 4; ++q) { acc[q][0] = 0.f; acc[q][1] = 0.f; }
    const int m01 = m[0] > m[1] ? m[0] : m[1];
    const int m23 = m[2] > m[3] ? m[2] : m[3];
    const int mmax = m01 > m23 ? m01 : m23;
    for (int j = 0; j < mmax; ++j) {
        #pragma unroll
        for (int q = 0; q < 4; ++q) {
            if (j < m[q]) {
                int2 p = csrw[beg[q] + j];
                float wq = __int_as_float(p.y);
                u16x2 u = *(const u16x2*)&t2[(size_t)p.x * OUT_C + ch];
                acc[q][0] += b2f(u[0]) * wq; acc[q][1] += b2f(u[1]) * wq;
            }
        }
    }
    float2 bb = *(const float2*)(b2 + ch);
    #pragma unroll
    for (int q = 0; q < 4; ++q) {
        int node = n0 + q;
        if (node < n)
            *(float2*)&out[(size_t)node * OUT_C + ch] =
                make_float2(acc[q][0] + bb.x, acc[q][1] + bb.y);
    }
}

extern "C" void kernel_launch(void* const* d_in, const int* in_sizes, int n_in,
                              void* d_out, int out_size, void* d_ws, size_t ws_size,
                              hipStream_t stream) {
    const float* x  = (const float*)d_in[0];
    const int*   ei = (const int*)d_in[1];
    const float* W1 = (const float*)d_in[2];
    const float* b1 = (const float*)d_in[3];
    const float* W2 = (const float*)d_in[4];
    const float* b2 = (const float*)d_in[5];
    float* out = (float*)d_out;

    const int n = in_sizes[0] / IN_C;   // 100000
    const int e = in_sizes[1] / 2;      // 300000
    const int* src = ei;
    const int* dst = ei + e;

    // workspace layout (4B words; csrw 8B-aligned, t1 16B-aligned)
    int*   cnt  = (int*)d_ws;                       // [n]
    int*   rs   = cnt + n;                          // [n]
    int*   cur  = rs + n;                           // [n]
    int*   bsum = cur + n;                          // [128]
    float* dinv = (float*)(bsum + 128);             // [n]
    int2*  csrw = (int2*)(dinv + n);                // [e+n] pairs {src, weight}
    unsigned short* W1T = (unsigned short*)(csrw + (size_t)e + n);  // [256*256]
    unsigned short* W2T = W1T + 65536;                              // [128*256]
    unsigned short* t1  = W2T + 32768;                              // [n*HID]
    unsigned short* out1 = t1 + (size_t)n * HID;                    // [n*HID]
    unsigned short* t2  = t1;                                       // alias

    const int nb = (n + SCAN_BS - 1) / SCAN_BS;

    k_zero_i<<<(n + 255) / 256, 256, 0, stream>>>(cnt, n);
    k_count<<<(e + 255) / 256, 256, 0, stream>>>(dst, cnt, e);
    k_scan_block<<<nb, SCAN_BS, 0, stream>>>(cnt, rs, bsum, n);
    k_scan_sums<<<1, 128, 0, stream>>>(bsum, nb);
    k_scan_add<<<(n + 255) / 256, 256, 0, stream>>>(rs, cur, bsum, cnt, dinv, csrw, n);
    k_fill<<<(e + 255) / 256, 256, 0, stream>>>(src, dst, dinv, cur, csrw, e);
    k_prep<<<256, 256, 0, stream>>>(W1, W2, W1T, W2T);

    const int mb = (n + 127) / 128;   // 782
    k_gemm1<<<mb, 512, 0, stream>>>(x, W1T, t1, n);
    const int aggblk = (n + 15) / 16;   // 16 nodes per block (4 waves x 4)
    k_agg1<<<aggblk, 256, 0, stream>>>(t1, rs, cnt, csrw, b1, out1, n);
    k_gemm2<<<mb, 256, 0, stream>>>(out1, W2T, t2, n);
    k_agg2<<<aggblk, 256, 0, stream>>>(t2, rs, cnt, csrw, b2, out, n);
}